// Round 4
// baseline (422.320 us; speedup 1.0000x reference)
//
#include <hip/hip_runtime.h>
#include <math.h>

#define RBINS 160
#define BROWS 65536
#define ROWELEMS 480                    // 160 bins * 3 channels
#define ROWF4 (ROWELEMS / 4)            // 120
#define TASKS_PER_ROW 20                // each task: 8 bins x 3 ch = 24 elements
#define NTHREADS 256
#define NBLOCKS_MAIN ((BROWS * TASKS_PER_ROW) / NTHREADS)   // 5120
#define NBLOCKS_FIX (BROWS / NTHREADS)                      // 256 (c==0 tasks)

typedef float f32x4 __attribute__((ext_vector_type(4)));

__device__ __forceinline__ float clamp01(float x) {
    return __builtin_amdgcn_fmed3f(x, 0.0f, 1.0f);
}

__device__ __forceinline__ void nt_store4(float* p, float a, float b, float c, float d) {
    f32x4 v = {a, b, c, d};
    __builtin_nontemporal_store(v, (f32x4*)p);
}

// One half (12 outputs) of the 4-tap stencil over a 36-float register window.
// P = wave-uniform misalignment (0..3), H = half (0/1). All indices compile-time.
template<int P, int H>
__device__ __forceinline__ void stencil_half(
    const float* __restrict__ w,
    float u1, float u2, float u3, float u4,
    float* __restrict__ r)
{
    #pragma unroll
    for (int m = 0; m < 12; ++m) {
        const int base = P + 12 * H + m;
        float acc = u1 * w[base];
        acc = fmaf(u2, w[base + 3], acc);
        acc = fmaf(u3, w[base + 6], acc);
        acc = fmaf(u4, w[base + 9], acc);
        r[m] = acc;
    }
}

template<int P>
__device__ __forceinline__ void compute_store24(
    const float* __restrict__ w,
    float u1, float u2, float u3, float u4,
    float* __restrict__ outp, bool fadeq, int bin0)
{
    float r[12];
    stencil_half<P, 0>(w, u1, u2, u3, u4, r);
    if (fadeq) {
        #pragma unroll
        for (int mb = 0; mb < 4; ++mb) {
            const int j = bin0 + mb;
            const float t = (float)(RBINS - 1 - j) * 0.125f;
            const float ff = (j >= RBINS - 8) ? t * t : 1.0f;
            r[3*mb+0] *= ff; r[3*mb+1] *= ff; r[3*mb+2] *= ff;
        }
    }
    nt_store4(outp + 0, r[0], r[1], r[2],  r[3]);
    nt_store4(outp + 4, r[4], r[5], r[6],  r[7]);
    nt_store4(outp + 8, r[8], r[9], r[10], r[11]);

    stencil_half<P, 1>(w, u1, u2, u3, u4, r);
    if (fadeq) {
        #pragma unroll
        for (int mb = 0; mb < 4; ++mb) {
            const int j = bin0 + 4 + mb;
            const float t = (float)(RBINS - 1 - j) * 0.125f;
            const float ff = (j >= RBINS - 8) ? t * t : 1.0f;
            r[3*mb+0] *= ff; r[3*mb+1] *= ff; r[3*mb+2] *= ff;
        }
    }
    nt_store4(outp + 12, r[0], r[1], r[2],  r[3]);
    nt_store4(outp + 16, r[4], r[5], r[6],  r[7]);
    nt_store4(outp + 20, r[8], r[9], r[10], r[11]);
}

// Injection of the 5-bin spread kernel into window elements with f in [0,15).
__device__ __forceinline__ void inject36(
    float* __restrict__ w, int a0,
    const float* __restrict__ color, int b,
    float aw0, float aw1, float aw2, float aw3, float aw4)
{
    const float c0 = color[3*b+0];
    const float c1 = color[3*b+1];
    const float c2 = color[3*b+2];
    #pragma unroll
    for (int u = 0; u < 36; ++u) {
        const int f = a0 + u;
        if ((unsigned)f < 15u) {
            const int bin = f / 3;
            const int ch  = f - 3 * bin;
            const float cv = (ch == 0) ? c0 : (ch == 1) ? c1 : c2;
            const float av = (bin == 0) ? aw0 : (bin == 1) ? aw1 :
                             (bin == 2) ? aw2 : (bin == 3) ? aw3 : aw4;
            w[u] += cv * av;
        }
    }
}

__global__ __launch_bounds__(NTHREADS, 4) void beat_kernel(
    const float* __restrict__ hist,
    const float* __restrict__ color,
    const float* __restrict__ p_offset,
    const float* __restrict__ p_persist,
    const float* __restrict__ p_diff,
    const float* __restrict__ p_dt,
    const float* __restrict__ p_amount,
    const float* __restrict__ p_spread,
    float* __restrict__ out)
{
    // ---- wave-uniform parameter math (mirrors ref f32 ops) ----
    const float offs = *p_offset;
    const float pers = *p_persist;
    const float diff = *p_diff;
    const float dts  = *p_dt;

    const float dt       = fminf(fmaxf(dts, 0.0f), 0.05f);
    const float dt_scale = dt * 60.0f;
    const float s        = offs * dt_scale;
    const float dt_pers  = __powf(pers, dt_scale);
    const int   dfl      = (int)floorf(s);
    const float frac     = s - (float)dfl;    // uniform: floor(i+s)=i+dfl interior
    const float kk = 0.15f * diff;
    const float cc = 1.0f - 2.0f * kk;
    const float wl = (1.0f - frac) * dt_pers;
    const float wr = frac * dt_pers;
    // interior 4-tap coefficients (taps t=1..4; t=0,5 identically zero)
    const float u1 = wr * kk;
    const float u2 = fmaf(wl, kk, wr * cc);
    const float u3 = fmaf(wl, cc, wr * kk);
    const float u4 = wl * kk;

    // valid source range as element range [flo, fhi)
    const int ilo = max(0, (int)ceilf(-s));
    const int ihi = min(RBINS - 1, (int)ceilf((float)(RBINS - 1) - s) - 1);
    const int flo = 3 * ilo;
    const int fhi = 3 * ihi + 3;

    int b, c, A;
    bool is_fix;
    if (blockIdx.x < NBLOCKS_MAIN) {
        const int task = blockIdx.x * NTHREADS + threadIdx.x;
        b = task / TASKS_PER_ROW;
        c = task - b * TASKS_PER_ROW;
        A = c * 24 - 6 - 3 * dfl;
        if (A < 15 && c < 1) return;          // fixup blocks own these
        is_fix = false;
    } else {
        b = (blockIdx.x - NBLOCKS_MAIN) * NTHREADS + threadIdx.x;
        c = 0;
        A = -6 - 3 * dfl;
        is_fix = true;
    }

    const int e0 = c * 24;
    const int p  = A & 3;                     // wave-uniform (dfl-only)
    const int a0 = A - p;                     // aligned window start
    const int q0 = a0 >> 2;

    // ---- 9 independent float4 loads, issued before any use (MLP) ----
    const float4* src4 = (const float4*)hist + (size_t)b * ROWF4;
    #define CLQ(q) min(max(q0 + (q), 0), ROWF4 - 1)
    const float4 v0 = src4[CLQ(0)];
    const float4 v1 = src4[CLQ(1)];
    const float4 v2 = src4[CLQ(2)];
    const float4 v3 = src4[CLQ(3)];
    const float4 v4 = src4[CLQ(4)];
    const float4 v5 = src4[CLQ(5)];
    const float4 v6 = src4[CLQ(6)];
    const float4 v7 = src4[CLQ(7)];
    const float4 v8 = src4[CLQ(8)];
    #undef CLQ

    float w[36];
    w[0]=v0.x; w[1]=v0.y; w[2]=v0.z; w[3]=v0.w;
    w[4]=v1.x; w[5]=v1.y; w[6]=v1.z; w[7]=v1.w;
    w[8]=v2.x; w[9]=v2.y; w[10]=v2.z; w[11]=v2.w;
    w[12]=v3.x; w[13]=v3.y; w[14]=v3.z; w[15]=v3.w;
    w[16]=v4.x; w[17]=v4.y; w[18]=v4.z; w[19]=v4.w;
    w[20]=v5.x; w[21]=v5.y; w[22]=v5.z; w[23]=v5.w;
    w[24]=v6.x; w[25]=v6.y; w[26]=v6.z; w[27]=v6.w;
    w[28]=v7.x; w[29]=v7.y; w[30]=v7.z; w[31]=v7.w;
    w[32]=v8.x; w[33]=v8.y; w[34]=v8.z; w[35]=v8.w;

    // ---- injection (fixup always checks; main only for extreme dfl) ----
    if (A < 15) {
        const float am = fminf(fmaxf(*p_amount, 0.0f), 1.0f);
        const float sp = fminf(fmaxf(*p_spread, 0.0f), 1.0f);
        const float tight = 1.0f - sp;
        inject36(w, a0, color, b,
                 am * fmaf(0.4f, tight, 0.5f), am * fmaf(0.2f, sp, 0.05f),
                 am * (0.12f * sp), am * (0.06f * sp), am * (0.02f * sp));
    }

    // ---- mask (valid source range) + clamp01 ----
    const int lo_u = flo - a0;
    const int hi_u = fhi - a0;
    #pragma unroll
    for (int u = 0; u < 36; ++u) {
        const bool v = (u >= lo_u) && (u < hi_u);
        w[u] = v ? clamp01(w[u]) : 0.0f;
    }

    if (is_fix && A >= 15) return;            // main owns this task then

    // ---- 4-tap stencil + fade + nontemporal float4 stores ----
    float* outp = out + (size_t)b * ROWELEMS + e0;
    const bool fadeq = (c == TASKS_PER_ROW - 1);   // bins >= 152
    const int bin0 = 8 * c;
    switch (p) {
        case 0:  compute_store24<0>(w, u1, u2, u3, u4, outp, fadeq, bin0); break;
        case 1:  compute_store24<1>(w, u1, u2, u3, u4, outp, fadeq, bin0); break;
        case 2:  compute_store24<2>(w, u1, u2, u3, u4, outp, fadeq, bin0); break;
        default: compute_store24<3>(w, u1, u2, u3, u4, outp, fadeq, bin0); break;
    }
}

extern "C" void kernel_launch(void* const* d_in, const int* in_sizes, int n_in,
                              void* d_out, int out_size, void* d_ws, size_t ws_size,
                              hipStream_t stream) {
    const float* hist      = (const float*)d_in[0];
    const float* color     = (const float*)d_in[1];
    const float* p_offset  = (const float*)d_in[2];
    const float* p_persist = (const float*)d_in[3];
    const float* p_diff    = (const float*)d_in[4];
    const float* p_dt      = (const float*)d_in[5];
    const float* p_amount  = (const float*)d_in[6];
    const float* p_spread  = (const float*)d_in[7];
    float* outp = (float*)d_out;

    beat_kernel<<<dim3(NBLOCKS_MAIN + NBLOCKS_FIX), dim3(NTHREADS), 0, stream>>>(
        hist, color, p_offset, p_persist, p_diff, p_dt, p_amount, p_spread, outp);
}

// Round 5
// 250.279 us; speedup vs baseline: 1.6874x; 1.6874x over previous
//
#include <hip/hip_runtime.h>
#include <math.h>

#define RBINS 160
#define BROWS 65536
#define ROWELEMS 480                    // 160 bins * 3 channels
#define ROWF4 (ROWELEMS / 4)            // 120
#define TASKS_PER_ROW 20                // each task: 8 bins x 3 ch = 24 elements
#define NTHREADS 256
#define NBLOCKS_MAIN ((BROWS * TASKS_PER_ROW) / NTHREADS)   // 5120
#define NBLOCKS_FIX (BROWS / NTHREADS)                      // 256 (c==0 tasks)

__device__ __forceinline__ float clamp01(float x) {
    return __builtin_amdgcn_fmed3f(x, 0.0f, 1.0f);
}

__device__ __forceinline__ void store4(float* p, float a, float b, float c, float d) {
    *(float4*)p = make_float4(a, b, c, d);
}

// One half (12 outputs) of the 4-tap stencil over a 36-float register window.
// P = wave-uniform misalignment (0..3), H = half (0/1). All indices compile-time.
template<int P, int H>
__device__ __forceinline__ void stencil_half(
    const float* __restrict__ w,
    float u1, float u2, float u3, float u4,
    float* __restrict__ r)
{
    #pragma unroll
    for (int m = 0; m < 12; ++m) {
        const int base = P + 12 * H + m;
        float acc = u1 * w[base];
        acc = fmaf(u2, w[base + 3], acc);
        acc = fmaf(u3, w[base + 6], acc);
        acc = fmaf(u4, w[base + 9], acc);
        r[m] = acc;
    }
}

template<int P>
__device__ __forceinline__ void compute_store24(
    const float* __restrict__ w,
    float u1, float u2, float u3, float u4,
    float* __restrict__ outp, bool fadeq, int bin0)
{
    float r[12];
    stencil_half<P, 0>(w, u1, u2, u3, u4, r);
    if (fadeq) {
        #pragma unroll
        for (int mb = 0; mb < 4; ++mb) {
            const int j = bin0 + mb;
            const float t = (float)(RBINS - 1 - j) * 0.125f;
            const float ff = (j >= RBINS - 8) ? t * t : 1.0f;
            r[3*mb+0] *= ff; r[3*mb+1] *= ff; r[3*mb+2] *= ff;
        }
    }
    store4(outp + 0, r[0], r[1], r[2],  r[3]);
    store4(outp + 4, r[4], r[5], r[6],  r[7]);
    store4(outp + 8, r[8], r[9], r[10], r[11]);

    stencil_half<P, 1>(w, u1, u2, u3, u4, r);
    if (fadeq) {
        #pragma unroll
        for (int mb = 0; mb < 4; ++mb) {
            const int j = bin0 + 4 + mb;
            const float t = (float)(RBINS - 1 - j) * 0.125f;
            const float ff = (j >= RBINS - 8) ? t * t : 1.0f;
            r[3*mb+0] *= ff; r[3*mb+1] *= ff; r[3*mb+2] *= ff;
        }
    }
    store4(outp + 12, r[0], r[1], r[2],  r[3]);
    store4(outp + 16, r[4], r[5], r[6],  r[7]);
    store4(outp + 20, r[8], r[9], r[10], r[11]);
}

// Injection of the 5-bin spread kernel into window elements with f in [0,15).
__device__ __forceinline__ void inject36(
    float* __restrict__ w, int a0,
    const float* __restrict__ color, int b,
    float aw0, float aw1, float aw2, float aw3, float aw4)
{
    const float c0 = color[3*b+0];
    const float c1 = color[3*b+1];
    const float c2 = color[3*b+2];
    #pragma unroll
    for (int u = 0; u < 36; ++u) {
        const int f = a0 + u;
        if ((unsigned)f < 15u) {
            const int bin = f / 3;
            const int ch  = f - 3 * bin;
            const float cv = (ch == 0) ? c0 : (ch == 1) ? c1 : c2;
            const float av = (bin == 0) ? aw0 : (bin == 1) ? aw1 :
                             (bin == 2) ? aw2 : (bin == 3) ? aw3 : aw4;
            w[u] += cv * av;
        }
    }
}

__global__ __launch_bounds__(NTHREADS, 4) void beat_kernel(
    const float* __restrict__ hist,
    const float* __restrict__ color,
    const float* __restrict__ p_offset,
    const float* __restrict__ p_persist,
    const float* __restrict__ p_diff,
    const float* __restrict__ p_dt,
    const float* __restrict__ p_amount,
    const float* __restrict__ p_spread,
    float* __restrict__ out)
{
    // ---- wave-uniform parameter math (mirrors ref f32 ops) ----
    const float offs = *p_offset;
    const float pers = *p_persist;
    const float diff = *p_diff;
    const float dts  = *p_dt;

    const float dt       = fminf(fmaxf(dts, 0.0f), 0.05f);
    const float dt_scale = dt * 60.0f;
    const float s        = offs * dt_scale;
    const float dt_pers  = __powf(pers, dt_scale);
    const int   dfl      = (int)floorf(s);
    const float frac     = s - (float)dfl;    // uniform: floor(i+s)=i+dfl interior
    const float kk = 0.15f * diff;
    const float cc = 1.0f - 2.0f * kk;
    const float wl = (1.0f - frac) * dt_pers;
    const float wr = frac * dt_pers;
    // interior 4-tap coefficients (taps t=1..4; t=0,5 identically zero)
    const float u1 = wr * kk;
    const float u2 = fmaf(wl, kk, wr * cc);
    const float u3 = fmaf(wl, cc, wr * kk);
    const float u4 = wl * kk;

    // valid source range as element range [flo, fhi)
    const int ilo = max(0, (int)ceilf(-s));
    const int ihi = min(RBINS - 1, (int)ceilf((float)(RBINS - 1) - s) - 1);
    const int flo = 3 * ilo;
    const int fhi = 3 * ihi + 3;

    int b, c, A;
    bool is_fix;
    if (blockIdx.x < NBLOCKS_MAIN) {
        const int task = blockIdx.x * NTHREADS + threadIdx.x;
        b = task / TASKS_PER_ROW;
        c = task - b * TASKS_PER_ROW;
        A = c * 24 - 6 - 3 * dfl;
        if (A < 15 && c < 1) return;          // fixup blocks own these
        is_fix = false;
    } else {
        b = (blockIdx.x - NBLOCKS_MAIN) * NTHREADS + threadIdx.x;
        c = 0;
        A = -6 - 3 * dfl;
        is_fix = true;
    }

    const int e0 = c * 24;
    const int p  = A & 3;                     // wave-uniform (dfl-only)
    const int a0 = A - p;                     // aligned window start
    const int q0 = a0 >> 2;

    // ---- 9 independent float4 loads, issued before any use (MLP) ----
    const float4* src4 = (const float4*)hist + (size_t)b * ROWF4;
    #define CLQ(q) min(max(q0 + (q), 0), ROWF4 - 1)
    const float4 v0 = src4[CLQ(0)];
    const float4 v1 = src4[CLQ(1)];
    const float4 v2 = src4[CLQ(2)];
    const float4 v3 = src4[CLQ(3)];
    const float4 v4 = src4[CLQ(4)];
    const float4 v5 = src4[CLQ(5)];
    const float4 v6 = src4[CLQ(6)];
    const float4 v7 = src4[CLQ(7)];
    const float4 v8 = src4[CLQ(8)];
    #undef CLQ

    float w[36];
    w[0]=v0.x; w[1]=v0.y; w[2]=v0.z; w[3]=v0.w;
    w[4]=v1.x; w[5]=v1.y; w[6]=v1.z; w[7]=v1.w;
    w[8]=v2.x; w[9]=v2.y; w[10]=v2.z; w[11]=v2.w;
    w[12]=v3.x; w[13]=v3.y; w[14]=v3.z; w[15]=v3.w;
    w[16]=v4.x; w[17]=v4.y; w[18]=v4.z; w[19]=v4.w;
    w[20]=v5.x; w[21]=v5.y; w[22]=v5.z; w[23]=v5.w;
    w[24]=v6.x; w[25]=v6.y; w[26]=v6.z; w[27]=v6.w;
    w[28]=v7.x; w[29]=v7.y; w[30]=v7.z; w[31]=v7.w;
    w[32]=v8.x; w[33]=v8.y; w[34]=v8.z; w[35]=v8.w;

    // ---- injection (fixup always checks; main only for extreme dfl) ----
    if (A < 15) {
        const float am = fminf(fmaxf(*p_amount, 0.0f), 1.0f);
        const float sp = fminf(fmaxf(*p_spread, 0.0f), 1.0f);
        const float tight = 1.0f - sp;
        inject36(w, a0, color, b,
                 am * fmaf(0.4f, tight, 0.5f), am * fmaf(0.2f, sp, 0.05f),
                 am * (0.12f * sp), am * (0.06f * sp), am * (0.02f * sp));
    }

    // ---- mask (valid source range) + clamp01 ----
    const int lo_u = flo - a0;
    const int hi_u = fhi - a0;
    #pragma unroll
    for (int u = 0; u < 36; ++u) {
        const bool v = (u >= lo_u) && (u < hi_u);
        w[u] = v ? clamp01(w[u]) : 0.0f;
    }

    if (is_fix && A >= 15) return;            // main owns this task then

    // ---- 4-tap stencil + fade + float4 stores ----
    float* outp = out + (size_t)b * ROWELEMS + e0;
    const bool fadeq = (c == TASKS_PER_ROW - 1);   // bins >= 152
    const int bin0 = 8 * c;
    switch (p) {
        case 0:  compute_store24<0>(w, u1, u2, u3, u4, outp, fadeq, bin0); break;
        case 1:  compute_store24<1>(w, u1, u2, u3, u4, outp, fadeq, bin0); break;
        case 2:  compute_store24<2>(w, u1, u2, u3, u4, outp, fadeq, bin0); break;
        default: compute_store24<3>(w, u1, u2, u3, u4, outp, fadeq, bin0); break;
    }
}

extern "C" void kernel_launch(void* const* d_in, const int* in_sizes, int n_in,
                              void* d_out, int out_size, void* d_ws, size_t ws_size,
                              hipStream_t stream) {
    const float* hist      = (const float*)d_in[0];
    const float* color     = (const float*)d_in[1];
    const float* p_offset  = (const float*)d_in[2];
    const float* p_persist = (const float*)d_in[3];
    const float* p_diff    = (const float*)d_in[4];
    const float* p_dt      = (const float*)d_in[5];
    const float* p_amount  = (const float*)d_in[6];
    const float* p_spread  = (const float*)d_in[7];
    float* outp = (float*)d_out;

    beat_kernel<<<dim3(NBLOCKS_MAIN + NBLOCKS_FIX), dim3(NTHREADS), 0, stream>>>(
        hist, color, p_offset, p_persist, p_diff, p_dt, p_amount, p_spread, outp);
}

// Round 6
// 244.397 us; speedup vs baseline: 1.7280x; 1.0241x over previous
//
#include <hip/hip_runtime.h>
#include <math.h>

#define RBINS 160
#define BROWS 65536
#define ROWELEMS 480                    // 160 bins * 3 channels
#define ROWF4 120
#define TILE_ROWS 16
#define TILE_F4 (TILE_ROWS * ROWF4)     // 1920 float4 staged per block
#define NTHREADS 320                    // 5 waves; 16 rows * 20 chunk-tasks
#define NBLOCKS (BROWS / TILE_ROWS)     // 4096
#define SROUNDS (TILE_F4 / NTHREADS)    // 6
#define LDS_SLOTS 2159                  // swz(1919) = 1919 + 239 = 2158

__device__ __forceinline__ float clamp01(float x) {
    return __builtin_amdgcn_fmed3f(x, 0.0f, 1.0f);
}

// additive bank-skew: logical f4 slot -> physical f4 slot
__device__ __forceinline__ int swz(int q) { return q + (q >> 3); }

// One half (12 outputs) of the 4-tap stencil over a 36-float register window.
template<int P, int H>
__device__ __forceinline__ void stencil_half(
    const float* __restrict__ w,
    float u1, float u2, float u3, float u4,
    float* __restrict__ r)
{
    #pragma unroll
    for (int m = 0; m < 12; ++m) {
        const int base = P + 12 * H + m;
        float acc = u1 * w[base];
        acc = fmaf(u2, w[base + 3], acc);
        acc = fmaf(u3, w[base + 6], acc);
        acc = fmaf(u4, w[base + 9], acc);
        r[m] = acc;
    }
}

template<int P>
__device__ __forceinline__ void compute_store24(
    const float* __restrict__ w,
    float u1, float u2, float u3, float u4,
    float* __restrict__ outp, bool fadeq, int bin0)
{
    float r[12];
    stencil_half<P, 0>(w, u1, u2, u3, u4, r);
    if (fadeq) {
        #pragma unroll
        for (int mb = 0; mb < 4; ++mb) {
            const int j = bin0 + mb;
            const float t = (float)(RBINS - 1 - j) * 0.125f;
            const float ff = (j >= RBINS - 8) ? t * t : 1.0f;
            r[3*mb+0] *= ff; r[3*mb+1] *= ff; r[3*mb+2] *= ff;
        }
    }
    *(float4*)(outp + 0) = make_float4(r[0], r[1], r[2],  r[3]);
    *(float4*)(outp + 4) = make_float4(r[4], r[5], r[6],  r[7]);
    *(float4*)(outp + 8) = make_float4(r[8], r[9], r[10], r[11]);

    stencil_half<P, 1>(w, u1, u2, u3, u4, r);
    if (fadeq) {
        #pragma unroll
        for (int mb = 0; mb < 4; ++mb) {
            const int j = bin0 + 4 + mb;
            const float t = (float)(RBINS - 1 - j) * 0.125f;
            const float ff = (j >= RBINS - 8) ? t * t : 1.0f;
            r[3*mb+0] *= ff; r[3*mb+1] *= ff; r[3*mb+2] *= ff;
        }
    }
    *(float4*)(outp + 12) = make_float4(r[0], r[1], r[2],  r[3]);
    *(float4*)(outp + 16) = make_float4(r[4], r[5], r[6],  r[7]);
    *(float4*)(outp + 20) = make_float4(r[8], r[9], r[10], r[11]);
}

// inject spread kernel into a staged float4 covering elements [4*c4, 4*c4+4)
// of its row; only elements f < 15 receive energy.
__device__ __forceinline__ void inject4(
    float4& v, int c4, float cl0, float cl1, float cl2,
    float aw0, float aw1, float aw2, float aw3, float aw4)
{
    float* vp = (float*)&v;
    #pragma unroll
    for (int k = 0; k < 4; ++k) {
        const int f = 4 * c4 + k;
        if (f < 15) {
            const int bin = f / 3;
            const int ch  = f - 3 * bin;
            const float cv = (ch == 0) ? cl0 : (ch == 1) ? cl1 : cl2;
            const float av = (bin == 0) ? aw0 : (bin == 1) ? aw1 :
                             (bin == 2) ? aw2 : (bin == 3) ? aw3 : aw4;
            vp[k] += cv * av;
        }
    }
}

__global__ __launch_bounds__(NTHREADS, 4) void beat_kernel(
    const float* __restrict__ hist,
    const float* __restrict__ color,
    const float* __restrict__ p_offset,
    const float* __restrict__ p_persist,
    const float* __restrict__ p_diff,
    const float* __restrict__ p_dt,
    const float* __restrict__ p_amount,
    const float* __restrict__ p_spread,
    float* __restrict__ out)
{
    __shared__ float4 tile[LDS_SLOTS];   // 34544 B, bank-skewed

    const int tid  = threadIdx.x;
    const int row0 = blockIdx.x * TILE_ROWS;

    // ---- wave-uniform parameter math (mirrors ref f32 ops) ----
    const float offs = *p_offset;
    const float pers = *p_persist;
    const float diff = *p_diff;
    const float dts  = *p_dt;

    const float dt       = fminf(fmaxf(dts, 0.0f), 0.05f);
    const float dt_scale = dt * 60.0f;
    const float s        = offs * dt_scale;
    const float dt_pers  = __powf(pers, dt_scale);
    const int   dfl      = (int)floorf(s);
    const float frac     = s - (float)dfl;    // uniform: floor(i+s)=i+dfl interior
    const float kk = 0.15f * diff;
    const float cc = 1.0f - 2.0f * kk;
    const float wl = (1.0f - frac) * dt_pers;
    const float wr = frac * dt_pers;
    const float u1 = wr * kk;
    const float u2 = fmaf(wl, kk, wr * cc);
    const float u3 = fmaf(wl, cc, wr * kk);
    const float u4 = wl * kk;

    // valid source range as element range [flo, fhi)
    const int ilo = max(0, (int)ceilf(-s));
    const int ihi = min(RBINS - 1, (int)ceilf((float)(RBINS - 1) - s) - 1);
    const int flo = 3 * ilo;
    const int fhi = 3 * ihi + 3;

    // injection weights (uniform)
    const float am = fminf(fmaxf(*p_amount, 0.0f), 1.0f);
    const float sp = fminf(fmaxf(*p_spread, 0.0f), 1.0f);
    const float tight = 1.0f - sp;
    const float aw0 = am * fmaf(0.4f, tight, 0.5f);
    const float aw1 = am * fmaf(0.2f, sp, 0.05f);
    const float aw2 = am * (0.12f * sp);
    const float aw3 = am * (0.06f * sp);
    const float aw4 = am * (0.02f * sp);

    // ---- staging: coalesced global float4 loads -> skewed LDS ----
    {
        const float4* src4 = (const float4*)hist + (size_t)row0 * ROWF4;
        // issue all 6 loads first (independent, in flight together)
        const int i0 = tid;
        const int i1 = tid + 1 * NTHREADS;
        const int i2 = tid + 2 * NTHREADS;
        const int i3 = tid + 3 * NTHREADS;
        const int i4 = tid + 4 * NTHREADS;
        const int i5 = tid + 5 * NTHREADS;
        float4 v0 = src4[i0];
        float4 v1 = src4[i1];
        float4 v2 = src4[i2];
        float4 v3 = src4[i3];
        float4 v4 = src4[i4];
        float4 v5 = src4[i5];

        #define STAGE(K)                                                     \
        {                                                                    \
            const int i  = i##K;                                             \
            const int rr = i / ROWF4;                                        \
            const int c4 = i - rr * ROWF4;                                   \
            if (c4 < 4) {                                                    \
                const float* cp = color + 3 * (row0 + rr);                   \
                inject4(v##K, c4, cp[0], cp[1], cp[2],                       \
                        aw0, aw1, aw2, aw3, aw4);                            \
            }                                                                \
            tile[swz(i)] = v##K;                                             \
        }
        STAGE(0) STAGE(1) STAGE(2) STAGE(3) STAGE(4) STAGE(5)
        #undef STAGE
    }
    __syncthreads();

    // ---- compute: one 24-element chunk (8 bins) per thread ----
    const int r  = tid / 20;
    const int c  = tid - r * 20;
    const int e0 = c * 24;
    const int A  = e0 - 6 - 3 * dfl;          // first tap element (row-local)
    const int p  = A & 3;                     // wave-uniform (dfl-only)
    const int a0 = A - p;                     // aligned window start (mult of 4)
    const int qc = a0 >> 2;                   // f4 index, may be <0 or >119
    const int base = r * ROWF4;

    float w[36];
    #pragma unroll
    for (int j = 0; j < 9; ++j) {
        const int qj = min(max(qc + j, 0), ROWF4 - 1);   // clamped; masked below
        const float4 v = tile[swz(base + qj)];
        w[4*j+0] = v.x; w[4*j+1] = v.y; w[4*j+2] = v.z; w[4*j+3] = v.w;
    }

    // mask (valid source range) + clamp01; fast path for interior lanes
    const int lo_u = flo - a0;
    const int hi_u = fhi - a0;
    if (lo_u > 0 || hi_u < 36) {
        #pragma unroll
        for (int u = 0; u < 36; ++u) {
            const bool v = (u >= lo_u) && (u < hi_u);
            w[u] = v ? clamp01(w[u]) : 0.0f;
        }
    } else {
        #pragma unroll
        for (int u = 0; u < 36; ++u) w[u] = clamp01(w[u]);
    }

    // 4-tap stencil + fade + float4 stores
    float* outp = out + (size_t)(row0 + r) * ROWELEMS + e0;
    const bool fadeq = (c == 19);             // bins >= 152
    const int bin0 = 8 * c;
    switch (p) {
        case 0:  compute_store24<0>(w, u1, u2, u3, u4, outp, fadeq, bin0); break;
        case 1:  compute_store24<1>(w, u1, u2, u3, u4, outp, fadeq, bin0); break;
        case 2:  compute_store24<2>(w, u1, u2, u3, u4, outp, fadeq, bin0); break;
        default: compute_store24<3>(w, u1, u2, u3, u4, outp, fadeq, bin0); break;
    }
}

extern "C" void kernel_launch(void* const* d_in, const int* in_sizes, int n_in,
                              void* d_out, int out_size, void* d_ws, size_t ws_size,
                              hipStream_t stream) {
    const float* hist      = (const float*)d_in[0];
    const float* color     = (const float*)d_in[1];
    const float* p_offset  = (const float*)d_in[2];
    const float* p_persist = (const float*)d_in[3];
    const float* p_diff    = (const float*)d_in[4];
    const float* p_dt      = (const float*)d_in[5];
    const float* p_amount  = (const float*)d_in[6];
    const float* p_spread  = (const float*)d_in[7];
    float* outp = (float*)d_out;

    beat_kernel<<<dim3(NBLOCKS), dim3(NTHREADS), 0, stream>>>(
        hist, color, p_offset, p_persist, p_diff, p_dt, p_amount, p_spread, outp);
}